// Round 1
// baseline (224.884 us; speedup 1.0000x reference)
//
#include <hip/hip_runtime.h>

// MHA: x[2,2048,1024] fp32; Q/K/V/O projections (y = x@W.T + b), 16 heads x 64,
// softmax(QK^T/8)V, output projection. All GEMMs + attention in bf16 MFMA,
// fp32 accumulate. Workspace: 48MB (bf16 copies + Q/K/Vt/O).

#define DIM 1024
#define NH 16
#define HD 64
#define SEQ 2048
#define NROWS 4096  // B*T

typedef unsigned short u16;
typedef __bf16 bf16_t;
typedef bf16_t bf16x8 __attribute__((ext_vector_type(8)));
typedef float f32x4 __attribute__((ext_vector_type(4)));
typedef u16 u16x4 __attribute__((ext_vector_type(4)));

typedef const __attribute__((address_space(1))) void* gas_ptr;
typedef __attribute__((address_space(3))) void* las_ptr;

// async global->LDS, 16B per lane. lds ptr must be wave-uniform base; HW
// writes lane i at base + i*16.
__device__ __forceinline__ void gl_lds16(const void* g, void* lds_wave_base) {
  __builtin_amdgcn_global_load_lds((gas_ptr)g, (las_ptr)lds_wave_base, 16, 0, 0);
}

__device__ __forceinline__ f32x4 mfma_bf16(bf16x8 a, bf16x8 b, f32x4 c) {
  return __builtin_amdgcn_mfma_f32_16x16x32_bf16(a, b, c, 0, 0, 0);
}

__device__ __forceinline__ u16 bfu(float f) {
  bf16_t b = (bf16_t)f;  // fptrunc, RNE
  union { bf16_t b; u16 u; } cv; cv.b = b; return cv.u;
}

// ---------------- fp32 -> bf16 conversion (vectorized) ----------------
__global__ void cvt_f32_bf16(const float* __restrict__ in, u16* __restrict__ out, int n4) {
  int i = blockIdx.x * 256 + threadIdx.x;
  if (i >= n4) return;
  float4 v = ((const float4*)in)[i];
  u16x4 o;
  o.x = bfu(v.x); o.y = bfu(v.y); o.z = bfu(v.z); o.w = bfu(v.w);
  ((u16x4*)out)[i] = o;
}

// ---------------- GEMM: C[4096,1024] = A[4096,1024] @ W[1024,1024]^T + bias --
// m97 structure: 128x128 tile, BK=32, 256 threads (4 waves, 2x2), each wave
// 64x64 via 4x4 frags of 16x16x32 MFMA. global_load_lds width-16 staging.
// MODE 0: bf16 row-major out. MODE 1: bf16 out written as Vt[b][h][d][t].
// MODE 2: f32 row-major out.
template <int MODE>
__global__ __launch_bounds__(256) void gemm_bt(const u16* __restrict__ A,
                                               const u16* __restrict__ W,
                                               const float* __restrict__ bias,
                                               void* __restrict__ Cout) {
  __shared__ u16 As[128 * 32];
  __shared__ u16 Bs[128 * 32];
  const int t = threadIdx.x, lane = t & 63, w = t >> 6;
  const int row0 = blockIdx.y * 128, col0 = blockIdx.x * 128;
  const int wr = w >> 1, wc = w & 1;
  const int lr = lane & 15, lk = lane >> 4;

  f32x4 acc[4][4] = {};

  for (int k0 = 0; k0 < DIM; k0 += 32) {
    if (k0) __syncthreads();  // protect previous tile from overwrite
#pragma unroll
    for (int i = 0; i < 2; ++i) {
      const int bc = i * 256 + w * 64;  // wave-uniform base chunk
      const int f = bc + lane;          // 16B chunk id: row = f>>2, col16 = f&3
      gl_lds16(A + (size_t)(row0 + (f >> 2)) * DIM + k0 + (f & 3) * 8, &As[bc * 8]);
      gl_lds16(W + (size_t)(col0 + (f >> 2)) * DIM + k0 + (f & 3) * 8, &Bs[bc * 8]);
    }
    __syncthreads();  // drains vmcnt -> staged data visible

    bf16x8 a[4], b[4];
#pragma unroll
    for (int m = 0; m < 4; ++m)
      a[m] = *(const bf16x8*)&As[(wr * 64 + m * 16 + lr) * 32 + lk * 8];
#pragma unroll
    for (int n = 0; n < 4; ++n)
      b[n] = *(const bf16x8*)&Bs[(wc * 64 + n * 16 + lr) * 32 + lk * 8];
#pragma unroll
    for (int m = 0; m < 4; ++m)
#pragma unroll
      for (int n = 0; n < 4; ++n)
        acc[m][n] = mfma_bf16(a[m], b[n], acc[m][n]);
  }

  // epilogue: C/D layout col=lane&15, row=(lane>>4)*4+reg (verified m89/m91)
#pragma unroll
  for (int m = 0; m < 4; ++m) {
    const int rowb = row0 + wr * 64 + m * 16 + lk * 4;
#pragma unroll
    for (int n = 0; n < 4; ++n) {
      const int col = col0 + wc * 64 + n * 16 + lr;
      const float bc = bias[col];
#pragma unroll
      for (int r = 0; r < 4; ++r) {
        const int rr = rowb + r;
        const float v = acc[m][n][r] + bc;
        if (MODE == 0) {
          ((u16*)Cout)[(size_t)rr * DIM + col] = bfu(v);
        } else if (MODE == 1) {
          // Vt[b][h][d][t]: b=rr>>11, t=rr&2047, h=col>>6, d=col&63
          const size_t idx = ((((size_t)(rr >> 11) * NH + (col >> 6)) * HD + (col & 63)) << 11) + (rr & 2047);
          ((u16*)Cout)[idx] = bfu(v);
        } else {
          ((float*)Cout)[(size_t)rr * DIM + col] = v;
        }
      }
    }
  }
}

// ---------------- flash attention ----------------
// grid (T/64, B*H); 256 thr = 4 waves; wave w owns q-rows [q0+w*16, +16).
// K/V tiles 64x64 bf16 staged with global_load_lds; 128B rows would be a
// 16-way bank conflict, so global source columns are pre-swizzled and reads
// XOR the chunk index with (row&7) (rule 21: linear dest + inv-swz source).
__global__ __launch_bounds__(256) void flash_attn(const u16* __restrict__ Q,
                                                  const u16* __restrict__ K,
                                                  const u16* __restrict__ Vt,
                                                  u16* __restrict__ O) {
  __shared__ u16 Ks[64 * 64];
  __shared__ u16 Vs[64 * 64];
  __shared__ u16 Ps[4 * 16 * 64];

  const int t = threadIdx.x, lane = t & 63, w = t >> 6;
  const int bh = blockIdx.y, b = bh >> 4, h = bh & 15;
  const int q0 = blockIdx.x * 64;
  const int lr = lane & 15, lk = lane >> 4;

  // Q fragments: A-layout row=lane&15, k=(lane>>4)*8+j; head-dim 64 = 2 chunks
  const size_t qrow = (size_t)(b * SEQ + q0 + w * 16 + lr);
  bf16x8 qf[2];
  qf[0] = *(const bf16x8*)&Q[qrow * DIM + h * HD + lk * 8];
  qf[1] = *(const bf16x8*)&Q[qrow * DIM + h * HD + lk * 8 + 32];

  f32x4 o[4] = {};
  float m0[4], l0[4];
#pragma unroll
  for (int r = 0; r < 4; ++r) { m0[r] = -INFINITY; l0[r] = 0.f; }

  u16* Pw = &Ps[w * 1024];

  for (int kt = 0; kt < SEQ; kt += 64) {
    __syncthreads();  // all waves done reading previous K/V tile
#pragma unroll
    for (int i = 0; i < 2; ++i) {
      const int bc = i * 256 + w * 64;
      const int f = bc + lane;
      const int row = f >> 3, c = f & 7;
      const int cs = c ^ (row & 7);  // pre-swizzled source column chunk
      gl_lds16(K + (size_t)(b * SEQ + kt + row) * DIM + h * HD + cs * 8, &Ks[bc * 8]);
      gl_lds16(Vt + (((size_t)bh * HD + row) << 11) + kt + cs * 8, &Vs[bc * 8]);
    }
    __syncthreads();

    // S = (Q K^T) * 0.125
    f32x4 s[4];
#pragma unroll
    for (int n = 0; n < 4; ++n) {
      s[n] = {};
#pragma unroll
      for (int kk = 0; kk < 2; ++kk) {
        const int row = n * 16 + lr;
        bf16x8 kf = *(const bf16x8*)&Ks[row * 64 + (((lk + kk * 4) ^ (row & 7)) * 8)];
        s[n] = mfma_bf16(qf[kk], kf, s[n]);
      }
      s[n] *= 0.125f;
    }

    // online softmax (rows of reg r live in the 16 lanes sharing lk)
    float p[4][4];
#pragma unroll
    for (int r = 0; r < 4; ++r) {
      float mx = fmaxf(fmaxf(s[0][r], s[1][r]), fmaxf(s[2][r], s[3][r]));
      mx = fmaxf(mx, __shfl_xor(mx, 1));
      mx = fmaxf(mx, __shfl_xor(mx, 2));
      mx = fmaxf(mx, __shfl_xor(mx, 4));
      mx = fmaxf(mx, __shfl_xor(mx, 8));
      const float mnew = fmaxf(m0[r], mx);
      const float alpha = __expf(m0[r] - mnew);
      m0[r] = mnew;
      float rs = 0.f;
#pragma unroll
      for (int n = 0; n < 4; ++n) { p[n][r] = __expf(s[n][r] - mnew); rs += p[n][r]; }
      rs += __shfl_xor(rs, 1);
      rs += __shfl_xor(rs, 2);
      rs += __shfl_xor(rs, 4);
      rs += __shfl_xor(rs, 8);
      l0[r] = l0[r] * alpha + rs;
#pragma unroll
      for (int n = 0; n < 4; ++n) o[n][r] *= alpha;
    }

    // P -> LDS (per-wave, swizzled), read back as A-frags
#pragma unroll
    for (int n = 0; n < 4; ++n)
#pragma unroll
      for (int r = 0; r < 4; ++r) {
        const int row = lk * 4 + r, col = n * 16 + lr;
        Pw[row * 64 + (col ^ ((row & 7) << 3))] = bfu(p[n][r]);
      }
#pragma unroll
    for (int kk = 0; kk < 2; ++kk) {
      bf16x8 pa = *(const bf16x8*)&Pw[lr * 64 + ((lk * 8 + kk * 32) ^ ((lr & 7) << 3))];
#pragma unroll
      for (int n = 0; n < 4; ++n) {
        const int vrow = n * 16 + lr;
        bf16x8 vf = *(const bf16x8*)&Vs[vrow * 64 + (((lk + kk * 4) ^ (vrow & 7)) * 8)];
        o[n] = mfma_bf16(pa, vf, o[n]);
      }
    }
  }

  // epilogue: normalize, write attention output [4096,1024] bf16
#pragma unroll
  for (int r = 0; r < 4; ++r) {
    const float inv = 1.f / l0[r];
    const size_t grow = (size_t)(b * SEQ + q0 + w * 16 + lk * 4 + r);
#pragma unroll
    for (int n = 0; n < 4; ++n)
      O[grow * DIM + h * HD + n * 16 + lr] = bfu(o[n][r] * inv);
  }
}

// ---------------- launch ----------------
extern "C" void kernel_launch(void* const* d_in, const int* in_sizes, int n_in,
                              void* d_out, int out_size, void* d_ws, size_t ws_size,
                              hipStream_t stream) {
  (void)in_sizes; (void)n_in; (void)out_size; (void)ws_size;
  const float* x  = (const float*)d_in[0];
  const float* Wq = (const float*)d_in[1];
  const float* bq = (const float*)d_in[2];
  const float* Wk = (const float*)d_in[3];
  const float* bk = (const float*)d_in[4];
  const float* Wv = (const float*)d_in[5];
  const float* bv = (const float*)d_in[6];
  const float* Wo = (const float*)d_in[7];
  const float* bo = (const float*)d_in[8];

  char* ws = (char*)d_ws;
  u16* xb  = (u16*)(ws + 0);         // 8MB
  u16* wqb = (u16*)(ws + 8388608);   // 2MB
  u16* wkb = (u16*)(ws + 10485760);  // 2MB
  u16* wvb = (u16*)(ws + 12582912);  // 2MB
  u16* wob = (u16*)(ws + 14680064);  // 2MB
  u16* Qb  = (u16*)(ws + 16777216);  // 8MB
  u16* Kb  = (u16*)(ws + 25165824);  // 8MB
  u16* Vtb = (u16*)(ws + 33554432);  // 8MB  (per-head transposed V)
  u16* Ob  = (u16*)(ws + 41943040);  // 8MB

  cvt_f32_bf16<<<(NROWS * DIM / 4 + 255) / 256, 256, 0, stream>>>(x, xb, NROWS * DIM / 4);
  cvt_f32_bf16<<<(DIM * DIM / 4 + 255) / 256, 256, 0, stream>>>(Wq, wqb, DIM * DIM / 4);
  cvt_f32_bf16<<<(DIM * DIM / 4 + 255) / 256, 256, 0, stream>>>(Wk, wkb, DIM * DIM / 4);
  cvt_f32_bf16<<<(DIM * DIM / 4 + 255) / 256, 256, 0, stream>>>(Wv, wvb, DIM * DIM / 4);
  cvt_f32_bf16<<<(DIM * DIM / 4 + 255) / 256, 256, 0, stream>>>(Wo, wob, DIM * DIM / 4);

  dim3 gg(DIM / 128, NROWS / 128);  // (8, 32)
  gemm_bt<0><<<gg, 256, 0, stream>>>(xb, wqb, bq, Qb);
  gemm_bt<0><<<gg, 256, 0, stream>>>(xb, wkb, bk, Kb);
  gemm_bt<1><<<gg, 256, 0, stream>>>(xb, wvb, bv, Vtb);

  flash_attn<<<dim3(SEQ / 64, 2 * NH), 256, 0, stream>>>(Qb, Kb, Vtb, Ob);

  gemm_bt<2><<<gg, 256, 0, stream>>>(Ob, wob, bo, d_out);
}

// Round 2
// 151.802 us; speedup vs baseline: 1.4814x; 1.4814x over previous
//
#include <hip/hip_runtime.h>

// MHA: x[2,2048,1024] fp32; Q/K/V/O projections (y = x@W.T + b), 16 heads x 64,
// softmax(QK^T/8)V, output projection. bf16 MFMA, fp32 accumulate.
// R2: swapped QK^T (in-lane softmax), QB=128 flash blocks, packed P-writes,
// scale folded into Wq/bq, fused QKV GEMM, fused weight converts.

#define DIM 1024
#define NH 16
#define HD 64
#define SEQ 2048
#define NROWS 4096  // B*T

typedef unsigned short u16;
typedef __bf16 bf16_t;
typedef bf16_t bf16x8 __attribute__((ext_vector_type(8)));
typedef float f32x4 __attribute__((ext_vector_type(4)));
typedef u16 u16x4 __attribute__((ext_vector_type(4)));

typedef const __attribute__((address_space(1))) void* gas_ptr;
typedef __attribute__((address_space(3))) void* las_ptr;

__device__ __forceinline__ void gl_lds16(const void* g, void* lds_wave_base) {
  __builtin_amdgcn_global_load_lds((gas_ptr)g, (las_ptr)lds_wave_base, 16, 0, 0);
}

__device__ __forceinline__ f32x4 mfma_bf16(bf16x8 a, bf16x8 b, f32x4 c) {
  return __builtin_amdgcn_mfma_f32_16x16x32_bf16(a, b, c, 0, 0, 0);
}

__device__ __forceinline__ u16 bfu(float f) {
  bf16_t b = (bf16_t)f;  // fptrunc, RNE
  union { bf16_t b; u16 u; } cv; cv.b = b; return cv.u;
}

// ---------------- fp32 -> bf16 converts ----------------
__global__ void cvt_x(const float* __restrict__ in, u16* __restrict__ out) {
  int i = blockIdx.x * 256 + threadIdx.x;
  float4 v = ((const float4*)in)[i];
  u16x4 o;
  o.x = bfu(v.x); o.y = bfu(v.y); o.z = bfu(v.z); o.w = bfu(v.w);
  ((u16x4*)out)[i] = o;
}

// all four weights in one launch; Wq scaled by 1/8 (exact, folds QK^T scale)
__global__ void cvt_w4(const float* __restrict__ wq, const float* __restrict__ wk,
                       const float* __restrict__ wv, const float* __restrict__ wo,
                       u16* __restrict__ oq, u16* __restrict__ ok,
                       u16* __restrict__ ov, u16* __restrict__ oo) {
  const int which = blockIdx.y;
  const float* in = which == 0 ? wq : which == 1 ? wk : which == 2 ? wv : wo;
  u16* out = which == 0 ? oq : which == 1 ? ok : which == 2 ? ov : oo;
  const float s = which == 0 ? 0.125f : 1.0f;
  int i = blockIdx.x * 256 + threadIdx.x;
  float4 v = ((const float4*)in)[i];
  u16x4 o;
  o.x = bfu(v.x * s); o.y = bfu(v.y * s); o.z = bfu(v.z * s); o.w = bfu(v.w * s);
  ((u16x4*)out)[i] = o;
}

// ---------------- fused QKV GEMM ----------------
// C[4096,1024] = A @ W.T + b for W in {Wq,Wk,Wv}; grid.x = 3*8 col-tiles.
// Q,K written row-major bf16; V written transposed per head: Vt[b][h][d][t].
__global__ __launch_bounds__(256) void gemm_qkv(const u16* __restrict__ A,
                                                const u16* __restrict__ wq,
                                                const u16* __restrict__ wk,
                                                const u16* __restrict__ wv,
                                                const float* __restrict__ bq,
                                                const float* __restrict__ bk,
                                                const float* __restrict__ bv,
                                                u16* __restrict__ Qb,
                                                u16* __restrict__ Kb,
                                                u16* __restrict__ Vtb) {
  __shared__ u16 As[128 * 32];
  __shared__ u16 Bs[128 * 32];
  const int which = blockIdx.x >> 3;          // 0=Q 1=K 2=V
  const int col0 = (blockIdx.x & 7) * 128;    // within the 1024 out cols
  const u16* W = which == 0 ? wq : which == 1 ? wk : wv;
  const float* bias = which == 0 ? bq : which == 1 ? bk : bv;
  const float bscale = which == 0 ? 0.125f : 1.0f;

  const int t = threadIdx.x, lane = t & 63, w = t >> 6;
  const int row0 = blockIdx.y * 128;
  const int wr = w >> 1, wc = w & 1;
  const int lr = lane & 15, lk = lane >> 4;

  f32x4 acc[4][4] = {};

  for (int k0 = 0; k0 < DIM; k0 += 32) {
    if (k0) __syncthreads();
#pragma unroll
    for (int i = 0; i < 2; ++i) {
      const int bc = i * 256 + w * 64;
      const int f = bc + lane;
      gl_lds16(A + (size_t)(row0 + (f >> 2)) * DIM + k0 + (f & 3) * 8, &As[bc * 8]);
      gl_lds16(W + (size_t)(col0 + (f >> 2)) * DIM + k0 + (f & 3) * 8, &Bs[bc * 8]);
    }
    __syncthreads();

    bf16x8 a[4], b[4];
#pragma unroll
    for (int m = 0; m < 4; ++m)
      a[m] = *(const bf16x8*)&As[(wr * 64 + m * 16 + lr) * 32 + lk * 8];
#pragma unroll
    for (int n = 0; n < 4; ++n)
      b[n] = *(const bf16x8*)&Bs[(wc * 64 + n * 16 + lr) * 32 + lk * 8];
#pragma unroll
    for (int m = 0; m < 4; ++m)
#pragma unroll
      for (int n = 0; n < 4; ++n)
        acc[m][n] = mfma_bf16(a[m], b[n], acc[m][n]);
  }

#pragma unroll
  for (int m = 0; m < 4; ++m) {
    const int rowb = row0 + wr * 64 + m * 16 + lk * 4;
#pragma unroll
    for (int n = 0; n < 4; ++n) {
      const int ocol = col0 + wc * 64 + n * 16 + lr;  // 0..1023
      const float bc = bias[ocol] * bscale;
#pragma unroll
      for (int r = 0; r < 4; ++r) {
        const int rr = rowb + r;
        const float v = acc[m][n][r] + bc;
        if (which == 0) {
          Qb[(size_t)rr * DIM + ocol] = bfu(v);
        } else if (which == 1) {
          Kb[(size_t)rr * DIM + ocol] = bfu(v);
        } else {
          // Vt[b][h][d][t]: b=rr>>11, t=rr&2047, h=ocol>>6, d=ocol&63
          const size_t idx = ((((size_t)(rr >> 11) * NH + (ocol >> 6)) * HD + (ocol & 63)) << 11) + (rr & 2047);
          Vtb[idx] = bfu(v);
        }
      }
    }
  }
}

// ---------------- output projection GEMM (fp32 out) ----------------
__global__ __launch_bounds__(256) void gemm_out(const u16* __restrict__ A,
                                                const u16* __restrict__ W,
                                                const float* __restrict__ bias,
                                                float* __restrict__ C) {
  __shared__ u16 As[128 * 32];
  __shared__ u16 Bs[128 * 32];
  const int t = threadIdx.x, lane = t & 63, w = t >> 6;
  const int row0 = blockIdx.y * 128, col0 = blockIdx.x * 128;
  const int wr = w >> 1, wc = w & 1;
  const int lr = lane & 15, lk = lane >> 4;

  f32x4 acc[4][4] = {};

  for (int k0 = 0; k0 < DIM; k0 += 32) {
    if (k0) __syncthreads();
#pragma unroll
    for (int i = 0; i < 2; ++i) {
      const int bc = i * 256 + w * 64;
      const int f = bc + lane;
      gl_lds16(A + (size_t)(row0 + (f >> 2)) * DIM + k0 + (f & 3) * 8, &As[bc * 8]);
      gl_lds16(W + (size_t)(col0 + (f >> 2)) * DIM + k0 + (f & 3) * 8, &Bs[bc * 8]);
    }
    __syncthreads();

    bf16x8 a[4], b[4];
#pragma unroll
    for (int m = 0; m < 4; ++m)
      a[m] = *(const bf16x8*)&As[(wr * 64 + m * 16 + lr) * 32 + lk * 8];
#pragma unroll
    for (int n = 0; n < 4; ++n)
      b[n] = *(const bf16x8*)&Bs[(wc * 64 + n * 16 + lr) * 32 + lk * 8];
#pragma unroll
    for (int m = 0; m < 4; ++m)
#pragma unroll
      for (int n = 0; n < 4; ++n)
        acc[m][n] = mfma_bf16(a[m], b[n], acc[m][n]);
  }

#pragma unroll
  for (int m = 0; m < 4; ++m) {
    const int rowb = row0 + wr * 64 + m * 16 + lk * 4;
#pragma unroll
    for (int n = 0; n < 4; ++n) {
      const int col = col0 + wc * 64 + n * 16 + lr;
      const float bc = bias[col];
#pragma unroll
      for (int r = 0; r < 4; ++r)
        C[(size_t)(rowb + r) * DIM + col] = acc[m][n][r] + bc;
    }
  }
}

// ---------------- flash attention (swapped QK^T, in-lane softmax) ----------
// grid (T/128, B*H); 4 waves; wave w owns q-rows [q0+w*32, +32) as 2 frags.
// S^T = mfma(K_frag, Q_frag): col=lane&15 -> q, row=(lane>>4)*4+r -> k.
// Each lane owns ONE q per frag: 16 in-lane k-values, reduce = 2 shuffles.
__global__ __launch_bounds__(256) void flash_attn(const u16* __restrict__ Q,
                                                  const u16* __restrict__ K,
                                                  const u16* __restrict__ Vt,
                                                  u16* __restrict__ O) {
  __shared__ u16 Ks[64 * 64];
  __shared__ u16 Vs[64 * 64];
  __shared__ u16 Ps[4][32][64];

  const int t = threadIdx.x, lane = t & 63, w = t >> 6;
  const int bh = blockIdx.y, b = bh >> 4, h = bh & 15;
  const int q0 = blockIdx.x * 128;
  const int lr = lane & 15, lk = lane >> 4;

  // Q B-frags (already scaled by 1/8 via Wq/bq): col=q, k=d
  bf16x8 qf[2][2];
#pragma unroll
  for (int qm = 0; qm < 2; ++qm) {
    const size_t qrow = (size_t)(b * SEQ + q0 + w * 32 + qm * 16 + lr);
    qf[qm][0] = *(const bf16x8*)&Q[qrow * DIM + h * HD + lk * 8];
    qf[qm][1] = *(const bf16x8*)&Q[qrow * DIM + h * HD + lk * 8 + 32];
  }

  f32x4 o[2][4] = {};
  float m0[2] = {-INFINITY, -INFINITY}, l0[2] = {0.f, 0.f};

  for (int kt = 0; kt < SEQ; kt += 64) {
    __syncthreads();  // all waves done reading previous K/V tile
#pragma unroll
    for (int i = 0; i < 2; ++i) {
      const int bc = i * 256 + w * 64;
      const int f = bc + lane;
      const int row = f >> 3, c = f & 7;
      const int cs = c ^ (row & 7);  // pre-swizzled source chunk (rule 21)
      gl_lds16(K + (size_t)(b * SEQ + kt + row) * DIM + h * HD + cs * 8, &Ks[bc * 8]);
      gl_lds16(Vt + (((size_t)bh * HD + row) << 11) + kt + cs * 8, &Vs[bc * 8]);
    }
    __syncthreads();

    // S^T: s[qm][n], q = qm*16+lr (col), k = n*16 + lk*4 + r (row)
    f32x4 s[2][4];
#pragma unroll
    for (int n = 0; n < 4; ++n) { s[0][n] = {}; s[1][n] = {}; }
#pragma unroll
    for (int n = 0; n < 4; ++n) {
#pragma unroll
      for (int kk = 0; kk < 2; ++kk) {
        const int row = n * 16 + lr;
        bf16x8 kf = *(const bf16x8*)&Ks[row * 64 + (((lk + kk * 4) ^ (row & 7)) * 8)];
        s[0][n] = mfma_bf16(kf, qf[0][kk], s[0][n]);
        s[1][n] = mfma_bf16(kf, qf[1][kk], s[1][n]);
      }
    }

    // online softmax: per lane, one q per qm; 16 in-lane k-values
#pragma unroll
    for (int qm = 0; qm < 2; ++qm) {
      f32x4 m4 = s[qm][0];
#pragma unroll
      for (int n = 1; n < 4; ++n) {
        m4[0] = fmaxf(m4[0], s[qm][n][0]); m4[1] = fmaxf(m4[1], s[qm][n][1]);
        m4[2] = fmaxf(m4[2], s[qm][n][2]); m4[3] = fmaxf(m4[3], s[qm][n][3]);
      }
      float mx = fmaxf(fmaxf(m4[0], m4[1]), fmaxf(m4[2], m4[3]));
      mx = fmaxf(mx, __shfl_xor(mx, 16));
      mx = fmaxf(mx, __shfl_xor(mx, 32));
      const float mnew = fmaxf(m0[qm], mx);
      const float alpha = __expf(m0[qm] - mnew);
      m0[qm] = mnew;

      float p[4][4];
      float rs = 0.f;
#pragma unroll
      for (int n = 0; n < 4; ++n)
#pragma unroll
        for (int r = 0; r < 4; ++r) { p[n][r] = __expf(s[qm][n][r] - mnew); rs += p[n][r]; }
      rs += __shfl_xor(rs, 16);
      rs += __shfl_xor(rs, 32);
      l0[qm] = l0[qm] * alpha + rs;

      // rescale o: its q-rows are lk*4+r -> pull alpha from lane lk*4+r
#pragma unroll
      for (int r = 0; r < 4; ++r) {
        const float a_r = __shfl(alpha, lk * 4 + r);
#pragma unroll
        for (int nd = 0; nd < 4; ++nd) o[qm][nd][r] *= a_r;
      }

      // P -> LDS, packed b64 (regs r = consecutive k), XOR-swizzled rows
      const int prow = qm * 16 + lr;
      const int rx = (lr & 7) << 3;
#pragma unroll
      for (int n = 0; n < 4; ++n) {
        u16x4 pk;
        pk.x = bfu(p[n][0]); pk.y = bfu(p[n][1]); pk.z = bfu(p[n][2]); pk.w = bfu(p[n][3]);
        *(u16x4*)&Ps[w][prow][(n * 16 + lk * 4) ^ rx] = pk;
      }
    }

    // PV: A = P[q][kv] frags, B = V^T (d-major) frags
#pragma unroll
    for (int kk = 0; kk < 2; ++kk) {
      const int rx = (lr & 7) << 3;
      bf16x8 pa0 = *(const bf16x8*)&Ps[w][lr][(kk * 32 + lk * 8) ^ rx];
      bf16x8 pa1 = *(const bf16x8*)&Ps[w][16 + lr][(kk * 32 + lk * 8) ^ rx];
#pragma unroll
      for (int nd = 0; nd < 4; ++nd) {
        const int vrow = nd * 16 + lr;
        bf16x8 vf = *(const bf16x8*)&Vs[vrow * 64 + (((lk + kk * 4) ^ (vrow & 7)) * 8)];
        o[0][nd] = mfma_bf16(pa0, vf, o[0][nd]);
        o[1][nd] = mfma_bf16(pa1, vf, o[1][nd]);
      }
    }
  }

  // epilogue: normalize (pull l from lane lk*4+r), write bf16 row-major
#pragma unroll
  for (int qm = 0; qm < 2; ++qm) {
#pragma unroll
    for (int r = 0; r < 4; ++r) {
      const float inv = 1.f / __shfl(l0[qm], lk * 4 + r);
      const size_t grow = (size_t)(b * SEQ + q0 + w * 32 + qm * 16 + lk * 4 + r);
#pragma unroll
      for (int nd = 0; nd < 4; ++nd)
        O[grow * DIM + h * HD + nd * 16 + lr] = bfu(o[qm][nd][r] * inv);
    }
  }
}

// ---------------- launch ----------------
extern "C" void kernel_launch(void* const* d_in, const int* in_sizes, int n_in,
                              void* d_out, int out_size, void* d_ws, size_t ws_size,
                              hipStream_t stream) {
  (void)in_sizes; (void)n_in; (void)out_size; (void)ws_size;
  const float* x  = (const float*)d_in[0];
  const float* Wq = (const float*)d_in[1];
  const float* bq = (const float*)d_in[2];
  const float* Wk = (const float*)d_in[3];
  const float* bk = (const float*)d_in[4];
  const float* Wv = (const float*)d_in[5];
  const float* bv = (const float*)d_in[6];
  const float* Wo = (const float*)d_in[7];
  const float* bo = (const float*)d_in[8];

  char* ws = (char*)d_ws;
  u16* xb  = (u16*)(ws + 0);         // 8MB
  u16* wqb = (u16*)(ws + 8388608);   // 2MB
  u16* wkb = (u16*)(ws + 10485760);  // 2MB
  u16* wvb = (u16*)(ws + 12582912);  // 2MB
  u16* wob = (u16*)(ws + 14680064);  // 2MB
  u16* Qb  = (u16*)(ws + 16777216);  // 8MB
  u16* Kb  = (u16*)(ws + 25165824);  // 8MB
  u16* Vtb = (u16*)(ws + 33554432);  // 8MB  (per-head transposed V)
  u16* Ob  = (u16*)(ws + 41943040);  // 8MB

  cvt_x<<<NROWS * DIM / 4 / 256, 256, 0, stream>>>(x, xb);
  cvt_w4<<<dim3(DIM * DIM / 4 / 256, 4), 256, 0, stream>>>(Wq, Wk, Wv, Wo, wqb, wkb, wvb, wob);

  gemm_qkv<<<dim3(24, NROWS / 128), 256, 0, stream>>>(xb, wqb, wkb, wvb, bq, bk, bv, Qb, Kb, Vtb);

  flash_attn<<<dim3(SEQ / 128, 2 * NH), 256, 0, stream>>>(Qb, Kb, Vtb, Ob);

  gemm_out<<<dim3(DIM / 128, NROWS / 128), 256, 0, stream>>>(Ob, wob, bo, (float*)d_out);
}